// Round 4
// baseline (515.604 us; speedup 1.0000x reference)
//
#include <hip/hip_runtime.h>
#include <hip/hip_bf16.h>
#include <hip/hip_cooperative_groups.h>

// PyramidLevel1Block: out[b,m,:] = relu(BN(W^T concat(pre_x[b,:,m], cur_x[b,:,idx]) + b))
// B=4, M=65536, N=16384, C_pre=64, C_cur=128, D=128.
//
// Phase 1: Z[b,n,:] = W_cur^T cur_x[b,:,n]  (only 65536 distinct gather targets)
// Phase 2: out = relu(scale*(W_pre^T pre_x[b,:,m] + Z[b,idx[b,m],:]) + shift)
// Fused into ONE cooperative kernel (grid.sync between phases) -> one dispatch,
// Z stays cache-resident (plain stores, NOT nontemporal: phase 2 re-reads it).
// 32-row tiles keep LDS at 13.3 KB so 1024 blocks are safely co-resident at
// __launch_bounds__(256,4). Fallback: same phases as two normal kernels.

namespace cg = cooperative_groups;

typedef short bhalf8 __attribute__((ext_vector_type(8)));
typedef float f32x4 __attribute__((ext_vector_type(4)));
typedef unsigned int u32x4 __attribute__((ext_vector_type(4)));

__device__ __forceinline__ short f2bf(float f) {
  unsigned int u = __float_as_uint(f);
  unsigned int r = (u + 0x7fffu + ((u >> 16) & 1u)) >> 16;
  return (short)r;
}
__device__ __forceinline__ float bf2f(short s) {
  return __uint_as_float(((unsigned int)(unsigned short)s) << 16);
}

#define ZST 136  // 128-col tile row stride (shorts): 272 B, 16B-aligned, 2-way banks only
#define PST 72   // 64-col pre tile row stride (shorts): 144 B, 16B-aligned
#define SMEM_SHORTS (32 * ZST + 32 * PST)  // 13312 B

// ---- phase 1 body: Z[b,n,d] = sum_c cur_x[b,c,n] * w[64+c][d], 32-row tiles ----
__device__ __forceinline__ void run_phase1(int bx, int nb, int tiles,
                                           const float* __restrict__ cur_x,
                                           const float* __restrict__ w,
                                           short* Z, short* tile_lds) {
  const int tid = threadIdx.x;
  const int lane = tid & 63;
  const int wv = tid >> 6;
  const int c = lane & 15;
  const int g = lane >> 4;

  bhalf8 bw[4][2];
#pragma unroll
  for (int s = 0; s < 4; ++s)
#pragma unroll
    for (int ct = 0; ct < 2; ++ct) {
      const int col = 32 * wv + 16 * ct + c;
#pragma unroll
      for (int j = 0; j < 8; ++j)
        bw[s][ct][j] = f2bf(w[(64 + 32 * s + 8 * g + j) * 128 + col]);
    }

  for (int t = 0; t < tiles; ++t) {
    const int r0 = (bx + t * nb) << 5;  // flat row = b*16384 + n, 32 rows/tile
    const int b = r0 >> 14;
    const int n0 = r0 & 16383;
    const float* src = cur_x + (size_t)b * 128 * 16384 + n0;
    if (t) __syncthreads();
    // stage 128 c x 32 n, coalesced f32x4 along n, transpose to LDS bf16
#pragma unroll
    for (int it = 0; it < 4; ++it) {
      int v = it * 256 + tid;
      int cc = v >> 3;         // 0..127
      int nq = (v & 7) << 2;   // 0..28
      f32x4 f = __builtin_nontemporal_load(
          reinterpret_cast<const f32x4*>(&src[(size_t)cc * 16384 + nq]));
#pragma unroll
      for (int k = 0; k < 4; ++k) tile_lds[(nq + k) * ZST + cc] = f2bf(f[k]);
    }
    __syncthreads();
    f32x4 acc[2][2];
#pragma unroll
    for (int rt = 0; rt < 2; ++rt) {
      bhalf8 a[4];
#pragma unroll
      for (int s = 0; s < 4; ++s)
        a[s] = *reinterpret_cast<const bhalf8*>(&tile_lds[(16 * rt + c) * ZST + 32 * s + 8 * g]);
      acc[rt][0] = (f32x4){0.f, 0.f, 0.f, 0.f};
      acc[rt][1] = (f32x4){0.f, 0.f, 0.f, 0.f};
#pragma unroll
      for (int s = 0; s < 4; ++s) {
        acc[rt][0] = __builtin_amdgcn_mfma_f32_16x16x32_bf16(a[s], bw[s][0], acc[rt][0], 0, 0, 0);
        acc[rt][1] = __builtin_amdgcn_mfma_f32_16x16x32_bf16(a[s], bw[s][1], acc[rt][1], 0, 0, 0);
      }
    }
    __syncthreads();
    // bounce D through LDS for coalesced stores
#pragma unroll
    for (int rt = 0; rt < 2; ++rt)
#pragma unroll
      for (int ct = 0; ct < 2; ++ct)
#pragma unroll
        for (int i = 0; i < 4; ++i)
          tile_lds[(16 * rt + 4 * g + i) * ZST + 32 * wv + 16 * ct + c] = f2bf(acc[rt][ct][i]);
    __syncthreads();
    // Z is re-read by phase 2: plain (cached) stores, 16B/lane coalesced
    short* dst = Z + (size_t)r0 * 128;
    const int row = tid >> 3, q = tid & 7;
#pragma unroll
    for (int u = 0; u < 2; ++u) {
      bhalf8 pk = *reinterpret_cast<const bhalf8*>(&tile_lds[row * ZST + q * 16 + 8 * u]);
      *reinterpret_cast<bhalf8*>(&dst[(size_t)row * 128 + q * 16 + 8 * u]) = pk;
    }
  }
}

// ---- phase 2 body: out = relu((W_pre^T pre_x + gather(Z))*scale + shift) ----
__device__ __forceinline__ void run_phase2(int bx, int nb, int tiles,
                                           const float* __restrict__ pre_x,
                                           const int* __restrict__ up_idx,
                                           const float* __restrict__ w,
                                           const float* __restrict__ bias,
                                           const float* __restrict__ gamma,
                                           const float* __restrict__ beta,
                                           const float* __restrict__ rmean,
                                           const float* __restrict__ rvar,
                                           const short* Z, float* __restrict__ out,
                                           short* z_lds, short* pre_lds) {
  const int tid = threadIdx.x;
  const int lane = tid & 63;
  const int wv = tid >> 6;
  const int c = lane & 15;
  const int g = lane >> 4;

  bhalf8 bw[2][2];
#pragma unroll
  for (int s = 0; s < 2; ++s)
#pragma unroll
    for (int ct = 0; ct < 2; ++ct) {
      const int col = 32 * wv + 16 * ct + c;
#pragma unroll
      for (int j = 0; j < 8; ++j)
        bw[s][ct][j] = f2bf(w[(32 * s + 8 * g + j) * 128 + col]);
    }
  float scale[2], shift[2];
#pragma unroll
  for (int ct = 0; ct < 2; ++ct) {
    const int d = 32 * wv + 16 * ct + c;
    float sc = gamma[d] * rsqrtf(rvar[d] + 1e-5f);
    scale[ct] = sc;
    shift[ct] = (bias[d] - rmean[d]) * sc + beta[d];
  }

  for (int t = 0; t < tiles; ++t) {
    const long rg = bx + (long)t * nb;  // 32-row tile id
    const long r0 = rg << 5;
    const int b = (int)(r0 >> 16);
    const int m0 = (int)(r0 & 65535);
    __syncthreads();  // LDS reuse fence (also covers first-iter reuse after phase 1)
    // stage pre_x: 64 c x 32 m, coalesced f32x4 along m, transpose to LDS bf16
    {
      const float* pb = pre_x + (size_t)b * 64 * 65536 + m0;
#pragma unroll
      for (int it = 0; it < 2; ++it) {
        int v = it * 256 + tid;
        int cc = v >> 3;        // 0..63
        int mq = (v & 7) << 2;  // 0..28
        f32x4 f = __builtin_nontemporal_load(
            reinterpret_cast<const f32x4*>(&pb[(size_t)cc * 65536 + mq]));
#pragma unroll
        for (int k = 0; k < 4; ++k) pre_lds[(mq + k) * PST + cc] = f2bf(f[k]);
      }
    }
    // stage gathered Z rows: 256 B contiguous per row (L2/L3-resident)
#pragma unroll
    for (int it = 0; it < 2; ++it) {
      int mm = it * 16 + (tid >> 4);
      int seg = tid & 15;
      int n = up_idx[r0 + mm];
      *reinterpret_cast<u32x4*>(&z_lds[mm * ZST + seg * 8]) =
          *reinterpret_cast<const u32x4*>(Z + ((size_t)b * 16384 + n) * 128 + seg * 8);
    }
    __syncthreads();
#pragma unroll
    for (int rt = 0; rt < 2; ++rt) {
      bhalf8 a[2];
#pragma unroll
      for (int s = 0; s < 2; ++s)
        a[s] = *reinterpret_cast<const bhalf8*>(&pre_lds[(16 * rt + c) * PST + 32 * s + 8 * g]);
      f32x4 acc0 = {0.f, 0.f, 0.f, 0.f};
      f32x4 acc1 = {0.f, 0.f, 0.f, 0.f};
#pragma unroll
      for (int s = 0; s < 2; ++s) {
        acc0 = __builtin_amdgcn_mfma_f32_16x16x32_bf16(a[s], bw[s][0], acc0, 0, 0, 0);
        acc1 = __builtin_amdgcn_mfma_f32_16x16x32_bf16(a[s], bw[s][1], acc1, 0, 0, 0);
      }
      float* ob = out + (size_t)(r0 + 16 * rt + 4 * g) * 128 + 32 * wv;
#pragma unroll
      for (int i = 0; i < 4; ++i) {
        const short* zr = &z_lds[(16 * rt + 4 * g + i) * ZST + 32 * wv];
        float v0 = fmaxf((acc0[i] + bf2f(zr[c])) * scale[0] + shift[0], 0.f);
        float v1 = fmaxf((acc1[i] + bf2f(zr[16 + c])) * scale[1] + shift[1], 0.f);
        __builtin_nontemporal_store(v0, ob + (size_t)i * 128 + c);
        __builtin_nontemporal_store(v1, ob + (size_t)i * 128 + 16 + c);
      }
    }
  }
}

// ---- cooperative fused kernel: 1024 blocks (4/CU co-resident) ----
__global__ __launch_bounds__(256, 4) void fused_all(
    const float* __restrict__ pre_x, const float* __restrict__ cur_x,
    const int* __restrict__ up_idx, const float* __restrict__ w,
    const float* __restrict__ bias, const float* __restrict__ gamma,
    const float* __restrict__ beta, const float* __restrict__ rmean,
    const float* __restrict__ rvar, short* Z, float* __restrict__ out) {
  __shared__ short smem[SMEM_SHORTS];
  run_phase1(blockIdx.x, 1024, 2, cur_x, w, Z, smem);
  __threadfence();  // device-scope release of Z before grid-wide barrier
  cg::this_grid().sync();
  run_phase2(blockIdx.x, 1024, 8, pre_x, up_idx, w, bias, gamma, beta, rmean, rvar,
             Z, out, smem, smem + 32 * ZST);
}

// ---- fallback pair (used only if cooperative launch is rejected) ----
__global__ __launch_bounds__(256, 4) void k_phase1(const float* __restrict__ cur_x,
                                                   const float* __restrict__ w,
                                                   short* Z) {
  __shared__ short smem[32 * ZST];
  run_phase1(blockIdx.x, 2048, 1, cur_x, w, Z, smem);
}
__global__ __launch_bounds__(256, 4) void k_phase2(
    const float* __restrict__ pre_x, const int* __restrict__ up_idx,
    const float* __restrict__ w, const float* __restrict__ bias,
    const float* __restrict__ gamma, const float* __restrict__ beta,
    const float* __restrict__ rmean, const float* __restrict__ rvar,
    const short* Z, float* __restrict__ out) {
  __shared__ short smem[SMEM_SHORTS];
  run_phase2(blockIdx.x, 2048, 4, pre_x, up_idx, w, bias, gamma, beta, rmean, rvar,
             Z, out, smem, smem + 32 * ZST);
}

extern "C" void kernel_launch(void* const* d_in, const int* in_sizes, int n_in,
                              void* d_out, int out_size, void* d_ws, size_t ws_size,
                              hipStream_t stream) {
  const float* pre_x = (const float*)d_in[0];
  const float* cur_x = (const float*)d_in[1];
  const int* up_idx = (const int*)d_in[2];
  const float* w = (const float*)d_in[3];
  const float* bias = (const float*)d_in[4];
  const float* gamma = (const float*)d_in[5];
  const float* beta = (const float*)d_in[6];
  const float* rmean = (const float*)d_in[7];
  const float* rvar = (const float*)d_in[8];
  float* out = (float*)d_out;
  short* Z = (short*)d_ws;  // (4, 16384, 128) bf16 = 16.8 MB

  void* args[11] = {&pre_x, &cur_x, &up_idx, &w,  &bias, &gamma,
                    &beta,  &rmean, &rvar,   &Z,  &out};
  hipError_t e = hipLaunchCooperativeKernel(fused_all, dim3(1024), dim3(256), args,
                                            0u, stream);
  if (e != hipSuccess) {
    hipLaunchKernelGGL(k_phase1, dim3(2048), dim3(256), 0, stream, cur_x, w, Z);
    hipLaunchKernelGGL(k_phase2, dim3(2048), dim3(256), 0, stream, pre_x, up_idx, w,
                       bias, gamma, beta, rmean, rvar, Z, out);
  }
}

// Round 5
// 246.576 us; speedup vs baseline: 2.0911x; 2.0911x over previous
//
#include <hip/hip_runtime.h>
#include <hip/hip_bf16.h>

// PyramidLevel1Block: out[b,m,:] = relu(BN(W^T concat(pre_x[b,:,m], cur_x[b,:,idx]) + b))
// B=4, M=65536, N=16384, C_pre=64, C_cur=128, D=128.
//
// Two-kernel plan (R4 post-mortem: cooperative/persistent = latency convoy, 3.5x
// slower; non-persistent blocks give free pipelining via block turnover):
//   K1: Z[b,n,:] = W_cur^T cur_x[b,:,n]   (65536 distinct gather targets only)
//       -> bf16 d_ws, CACHED stores (k2 re-reads Z randomly; keep L2/L3-resident)
//   K2: out = relu(scale*(W_pre^T pre_x[b,:,m] + Z[b,idx[b,m],:]) + shift)
//       4096 one-tile blocks; ALL staging loads hoisted to registers before any
//       LDS write (idx -> pre -> Z issued back-to-back: ~2 serialized round trips).

typedef short bhalf8 __attribute__((ext_vector_type(8)));
typedef float f32x4 __attribute__((ext_vector_type(4)));
typedef unsigned int u32x4 __attribute__((ext_vector_type(4)));

__device__ __forceinline__ short f2bf(float f) {
  unsigned int u = __float_as_uint(f);
  unsigned int r = (u + 0x7fffu + ((u >> 16) & 1u)) >> 16;
  return (short)r;
}
__device__ __forceinline__ float bf2f(short s) {
  return __uint_as_float(((unsigned int)(unsigned short)s) << 16);
}

#define ZST 136  // 128-col LDS row stride (shorts): 272 B, 16B-aligned
#define PST 72   // 64-col LDS row stride (shorts): 144 B, 16B-aligned

// ---------------- K1: Z[b,n,d] = sum_c cur_x[b,c,n] * w[64+c][d], bf16 out --------
__global__ __launch_bounds__(256) void cur_gemm(const float* __restrict__ cur,
                                                const float* __restrict__ w,
                                                short* __restrict__ Z) {
  __shared__ short lds[64 * ZST];  // A-tile [64 n][128 c], then D-tile [64 n][128 d]
  const int tid = threadIdx.x;
  const int lane = tid & 63;
  const int wv = tid >> 6;
  const int c = lane & 15;
  const int g = lane >> 4;
  const int r0 = blockIdx.x << 6;  // flat row = b*16384 + n
  const int b = r0 >> 14;
  const int n0 = r0 & 16383;
  const float* src = cur + (size_t)b * 128 * 16384 + n0;

  // W fragments (cur rows 64..191)
  bhalf8 bw[4][2];
#pragma unroll
  for (int s = 0; s < 4; ++s)
#pragma unroll
    for (int ct = 0; ct < 2; ++ct) {
      const int col = 32 * wv + 16 * ct + c;
#pragma unroll
      for (int j = 0; j < 8; ++j)
        bw[s][ct][j] = f2bf(w[(64 + 32 * s + 8 * g + j) * 128 + col]);
    }

  // stage cur tile: 128 c x 64 n; hoist all 8 loads before LDS writes
  f32x4 cf[8];
#pragma unroll
  for (int it = 0; it < 8; ++it) {
    int v = it * 256 + tid;
    cf[it] = __builtin_nontemporal_load(
        reinterpret_cast<const f32x4*>(&src[(size_t)(v >> 4) * 16384 + ((v & 15) << 2)]));
  }
#pragma unroll
  for (int it = 0; it < 8; ++it) {
    int v = it * 256 + tid;
    int cc = v >> 4;
    int nq = (v & 15) << 2;
#pragma unroll
    for (int k = 0; k < 4; ++k) lds[(nq + k) * ZST + cc] = f2bf(cf[it][k]);
  }
  __syncthreads();

  f32x4 acc[4][2];
#pragma unroll
  for (int rt = 0; rt < 4; ++rt) {
    bhalf8 a[4];
#pragma unroll
    for (int s = 0; s < 4; ++s)
      a[s] = *reinterpret_cast<const bhalf8*>(&lds[(16 * rt + c) * ZST + 32 * s + 8 * g]);
    acc[rt][0] = (f32x4){0.f, 0.f, 0.f, 0.f};
    acc[rt][1] = (f32x4){0.f, 0.f, 0.f, 0.f};
#pragma unroll
    for (int s = 0; s < 4; ++s) {
      acc[rt][0] = __builtin_amdgcn_mfma_f32_16x16x32_bf16(a[s], bw[s][0], acc[rt][0], 0, 0, 0);
      acc[rt][1] = __builtin_amdgcn_mfma_f32_16x16x32_bf16(a[s], bw[s][1], acc[rt][1], 0, 0, 0);
    }
  }
  __syncthreads();
  // bounce D through LDS for coalesced bf16 stores
#pragma unroll
  for (int rt = 0; rt < 4; ++rt)
#pragma unroll
    for (int ct = 0; ct < 2; ++ct)
#pragma unroll
      for (int i = 0; i < 4; ++i)
        lds[(16 * rt + 4 * g + i) * ZST + 32 * wv + 16 * ct + c] = f2bf(acc[rt][ct][i]);
  __syncthreads();
  // CACHED stores: Z must stay L2/L3-resident for K2's gather
  short* dst = Z + (size_t)r0 * 128;
  const int row = tid >> 2, q = tid & 3;
#pragma unroll
  for (int u = 0; u < 4; ++u)
    *reinterpret_cast<bhalf8*>(&dst[(size_t)row * 128 + q * 32 + 8 * u]) =
        *reinterpret_cast<const bhalf8*>(&lds[row * ZST + q * 32 + 8 * u]);
}

// ---------------- K2: fused pre-GEMM + Z gather + BN + ReLU -----------------------
__global__ __launch_bounds__(256) void fused_main(
    const float* __restrict__ pre_x,  // (4, 64, 65536)
    const int* __restrict__ up_idx,   // (4, 65536)
    const float* __restrict__ w,      // (192, 128)
    const float* __restrict__ bias, const float* __restrict__ gamma,
    const float* __restrict__ beta, const float* __restrict__ rmean,
    const float* __restrict__ rvar,
    const short* __restrict__ Z,  // (4, 16384, 128) bf16
    float* __restrict__ out)      // (4, 65536, 128) f32
{
  __shared__ short pre_lds[64 * PST];  // [64 m][64 k]
  __shared__ short z_lds[64 * ZST];    // [64 m][128 d]
  const int tid = threadIdx.x;
  const int lane = tid & 63;
  const int wv = tid >> 6;
  const int c = lane & 15;
  const int g = lane >> 4;
  const int r0 = blockIdx.x << 6;  // flat row = b*65536 + m
  const int b = r0 >> 16;
  const int m0 = r0 & 65535;

  // ---- staging: issue ALL global loads before any LDS write ----
  int ns[4];
#pragma unroll
  for (int it = 0; it < 4; ++it) ns[it] = up_idx[r0 + it * 16 + (tid >> 4)];
  const float* pb = pre_x + (size_t)b * 64 * 65536 + m0;
  f32x4 pf[4];
#pragma unroll
  for (int it = 0; it < 4; ++it) {
    int v = it * 256 + tid;
    pf[it] = __builtin_nontemporal_load(
        reinterpret_cast<const f32x4*>(&pb[(size_t)(v >> 4) * 65536 + ((v & 15) << 2)]));
  }
  u32x4 zf[4];
#pragma unroll
  for (int it = 0; it < 4; ++it)
    zf[it] = *reinterpret_cast<const u32x4*>(
        Z + ((size_t)b * 16384 + ns[it]) * 128 + (tid & 15) * 8);

  // W fragments (pre rows 0..63) + folded BN constants — computed while loads fly
  bhalf8 bw[2][2];
#pragma unroll
  for (int s = 0; s < 2; ++s)
#pragma unroll
    for (int ct = 0; ct < 2; ++ct) {
      const int col = 32 * wv + 16 * ct + c;
#pragma unroll
      for (int j = 0; j < 8; ++j)
        bw[s][ct][j] = f2bf(w[(32 * s + 8 * g + j) * 128 + col]);
    }
  float scale[2], shift[2];
#pragma unroll
  for (int ct = 0; ct < 2; ++ct) {
    const int d = 32 * wv + 16 * ct + c;
    float sc = gamma[d] * rsqrtf(rvar[d] + 1e-5f);
    scale[ct] = sc;
    shift[ct] = (bias[d] - rmean[d]) * sc + beta[d];
  }

  // ---- LDS writes ----
#pragma unroll
  for (int it = 0; it < 4; ++it) {
    int v = it * 256 + tid;
    int cc = v >> 4;
    int mq = (v & 15) << 2;
#pragma unroll
    for (int k = 0; k < 4; ++k) pre_lds[(mq + k) * PST + cc] = f2bf(pf[it][k]);
  }
#pragma unroll
  for (int it = 0; it < 4; ++it)
    *reinterpret_cast<u32x4*>(&z_lds[(it * 16 + (tid >> 4)) * ZST + (tid & 15) * 8]) =
        zf[it];
  __syncthreads();

  // ---- compute + fused epilogue ----
#pragma unroll
  for (int rt = 0; rt < 4; ++rt) {
    bhalf8 a[2];
#pragma unroll
    for (int s = 0; s < 2; ++s)
      a[s] = *reinterpret_cast<const bhalf8*>(
          &pre_lds[(16 * rt + c) * PST + 32 * s + 8 * g]);
    f32x4 acc0 = {0.f, 0.f, 0.f, 0.f};
    f32x4 acc1 = {0.f, 0.f, 0.f, 0.f};
#pragma unroll
    for (int s = 0; s < 2; ++s) {
      acc0 = __builtin_amdgcn_mfma_f32_16x16x32_bf16(a[s], bw[s][0], acc0, 0, 0, 0);
      acc1 = __builtin_amdgcn_mfma_f32_16x16x32_bf16(a[s], bw[s][1], acc1, 0, 0, 0);
    }
    float* ob = out + (size_t)(r0 + 16 * rt + 4 * g) * 128 + 32 * wv;
#pragma unroll
    for (int i = 0; i < 4; ++i) {
      const short* zr = &z_lds[(16 * rt + 4 * g + i) * ZST + 32 * wv];
      float v0 = fmaxf((acc0[i] + bf2f(zr[c])) * scale[0] + shift[0], 0.f);
      float v1 = fmaxf((acc1[i] + bf2f(zr[16 + c])) * scale[1] + shift[1], 0.f);
      __builtin_nontemporal_store(v0, ob + (size_t)i * 128 + c);
      __builtin_nontemporal_store(v1, ob + (size_t)i * 128 + 16 + c);
    }
  }
}

extern "C" void kernel_launch(void* const* d_in, const int* in_sizes, int n_in,
                              void* d_out, int out_size, void* d_ws, size_t ws_size,
                              hipStream_t stream) {
  const float* pre_x = (const float*)d_in[0];
  const float* cur_x = (const float*)d_in[1];
  const int* up_idx = (const int*)d_in[2];
  const float* w = (const float*)d_in[3];
  const float* bias = (const float*)d_in[4];
  const float* gamma = (const float*)d_in[5];
  const float* beta = (const float*)d_in[6];
  const float* rmean = (const float*)d_in[7];
  const float* rvar = (const float*)d_in[8];
  float* out = (float*)d_out;
  short* Z = (short*)d_ws;  // (4, 16384, 128) bf16 = 16.8 MB

  hipLaunchKernelGGL(cur_gemm, dim3(1024), dim3(256), 0, stream, cur_x, w, Z);
  hipLaunchKernelGGL(fused_main, dim3(4096), dim3(256), 0, stream, pre_x, up_idx, w,
                     bias, gamma, beta, rmean, rvar, Z, out);
}